// Round 3
// baseline (351.796 us; speedup 1.0000x reference)
//
#include <hip/hip_runtime.h>
#include <cstdint>

typedef __attribute__((ext_vector_type(8))) short bf16x8;
typedef __attribute__((ext_vector_type(4))) float f32x4;

__device__ __forceinline__ unsigned short f2bf(float v) {
  unsigned u = __builtin_bit_cast(unsigned, v);
  u += 0x7FFFu + ((u >> 16) & 1u);   // RNE
  return (unsigned short)(u >> 16);
}

// async global->LDS, 16B per lane; LDS dest = wave-uniform base + lane*16
__device__ __forceinline__ void gload16(const unsigned short* g, unsigned short* l) {
  __builtin_amdgcn_global_load_lds(
      (const __attribute__((address_space(1))) void*)(uintptr_t)g,
      (__attribute__((address_space(3))) void*)(uint32_t)(uintptr_t)l,
      16, 0, 0);
}

// Inline-asm ds_read_b128: keeps the LDS fragment loads OUT of the compiler's
// waitcnt bookkeeping. Plain C++ LDS reads alias-analyze against the in-flight
// global_load_lds writes and get a compiler-inserted vmcnt(0) drain -> every
// phase exposes full global latency (the r1/r2 regression). Asm reads don't.
__device__ __forceinline__ bf16x8 ds_read128(const unsigned short* p) {
  bf16x8 r;
  asm volatile("ds_read_b128 %0, %1"
               : "=v"(r)
               : "v"((uint32_t)(uintptr_t)p));
  return r;
}

// raw barrier (no implicit vmcnt(0) drain) + counted waits
#define BAR()   asm volatile("s_barrier" ::: "memory")
// rule #18: sched_barrier(0) right after lgkmcnt(0) — hipcc otherwise hoists
// register-only MFMAs between the asm ds_read and the asm waitcnt (HW writes
// the ds_read dest register only at retire; data-dep alone doesn't order it).
#define LGKM0() do { asm volatile("s_waitcnt lgkmcnt(0)" ::: "memory"); \
                     __builtin_amdgcn_sched_barrier(0); } while (0)
#define VMW(N)  asm volatile("s_waitcnt vmcnt(" #N ")" ::: "memory")

// m201-geometry bf16 NT GEMM core: C[256x256] += A[256xK] * B[256xK]^T, BK=64.
// 512 threads = 8 waves (2M x 4N); per-wave 128x64 output, acc[8][4].
//
// LDS: 8 half-tile slots x 16 KiB (128 KiB). Half = 128 rows x 64 bf16,
// XOR-swizzled 16B chunks (chunk c of row r at physical c^(r&7)) -> conflict-
// free ds_read_b128; staging stays lane-contiguous for global_load_lds
// (source chunk pre-swizzled). Half stream h: tile h>>2, part h&3
// {0:B0,1:B1,2:A0,3:A1}; slot(h) = h mod 8 -> tile t in slots (t&1)*4+part.
//
// Schedule: 4 phases per K-tile, 16 MFMA each.
//  ph0: read all B (8xb128) + A frags 0,1 (4); stage A0(t+1)
//  ph1: read A frags 2,3;                      stage A1(t+1)
//  ph2: read A frags 4,5;                      stage B0(t+2)
//  ph3: read A frags 6,7;                      stage B1(t+2)
//  each phase: reads; stage; BAR; lgkmcnt(0)+sched_barrier; setprio1; 16 MFMA;
//              setprio0; [ph3 only: vmcnt(4), or vmcnt(0) at t==NT-2]; BAR
// vmcnt audit (steady state): entering tile t, outstanding = B(t+1) halves
// (4 loads). ph0/ph1 add A(t+1) (4), ph2/ph3 add B(t+2) (4) -> 12; vmcnt(4)
// at ph3 forces B(t+1)+A(t+1) landed, leaves B(t+2) in flight. So tile t+1's
// reads always hit landed data, and vmcnt never drains to 0 mid-loop.
// Slot-overwrite hazard: every staged slot's last reader finished >=2
// barriers earlier (B(t) last read ph0, overwritten ph2/ph3; A(t) last read
// ph3, overwritten ph0/ph1 of t+1; per-wave lgkmcnt(0) before its MFMAs
// guarantees its ds_reads retired before it can issue the overwriting stage).
__device__ __forceinline__ void gemm_core(
    const unsigned short* __restrict__ A, const unsigned short* __restrict__ B,
    int lda, int ldb, int NT,
    unsigned short* lds, f32x4 acc[8][4])
{
  const int tid  = threadIdx.x;
  const int w    = tid >> 6;
  const int lane = tid & 63;
  const int wr   = w >> 2;        // 0..1  (M)
  const int wc   = w & 3;         // 0..3  (N)
  const int lrow = lane & 15;
  const int kq   = lane >> 4;

  // staging: thread t covers half-row (t>>3) per 8KB round, swizzled chunk
  const int srow = tid >> 3;                        // 0..63
  const int schk = ((tid & 7) ^ (srow & 7)) * 8;    // pre-swizzled source chunk
  const unsigned short* gA = A + (long)srow * lda + schk;
  const unsigned short* gB = B + (long)srow * ldb + schk;
  unsigned short* const stg = lds + w * 512;        // + slot*8192 + round*4096

  const int pc0 = ((0 + kq) ^ (lrow & 7)) * 8;      // k-step 0 physical chunk
  const int pc1 = ((4 + kq) ^ (lrow & 7)) * 8;      // k-step 1 physical chunk

  // stage one half (2 gloads): operand g/ld, half row-offset H, tile t, slot s
  #define STG(g, ld, H, t, s) do { \
    gload16((g) + (long)(H)      * (ld) + (t) * 64, stg + (s) * 8192); \
    gload16((g) + (long)((H)+64) * (ld) + (t) * 64, stg + (s) * 8192 + 4096); \
  } while (0)

  // prologue: halves 0..5 in stream order
  STG(gB, ldb, 0,   0, 0);   // B0(0)
  STG(gB, ldb, 128, 0, 1);   // B1(0)
  STG(gA, lda, 0,   0, 2);   // A0(0)
  STG(gA, lda, 128, 0, 3);   // A1(0)
  STG(gB, ldb, 0,   1, 4);   // B0(1)
  STG(gB, ldb, 128, 1, 5);   // B1(1)
  VMW(4);                    // tile 0 (halves 0..3) landed
  BAR();

  for (int t = 0; t < NT; ++t) {
    const int base = (t & 1) * 32768;   // 4 slots * 8192 shorts
    const unsigned short* lA = lds + base + (2 + wr) * 8192 + lrow * 64;
    const unsigned short* lB = lds + base + (wc >> 1) * 8192 + ((wc & 1) * 64 + lrow) * 64;
    const bool doA = (t + 1 < NT);
    const bool doB = (t + 2 < NT);

    bf16x8 bfr[4][2], af[2][2];
#pragma unroll
    for (int p = 0; p < 4; ++p) {
      if (p == 0) {
#pragma unroll
        for (int j = 0; j < 4; ++j) {
          bfr[j][0] = ds_read128(lB + j * 1024 + pc0);
          bfr[j][1] = ds_read128(lB + j * 1024 + pc1);
        }
      }
#pragma unroll
      for (int i = 0; i < 2; ++i) {
        af[i][0] = ds_read128(lA + (2 * p + i) * 1024 + pc0);
        af[i][1] = ds_read128(lA + (2 * p + i) * 1024 + pc1);
      }
      if (p == 0 && doA) STG(gA, lda, 0,   t + 1, ((t + 1) & 1) * 4 + 2);
      if (p == 1 && doA) STG(gA, lda, 128, t + 1, ((t + 1) & 1) * 4 + 3);
      if (p == 2 && doB) STG(gB, ldb, 0,   t + 2, (t & 1) * 4 + 0);
      if (p == 3 && doB) STG(gB, ldb, 128, t + 2, (t & 1) * 4 + 1);
      BAR();
      LGKM0();
      __builtin_amdgcn_s_setprio(1);
#pragma unroll
      for (int i = 0; i < 2; ++i)
#pragma unroll
        for (int j = 0; j < 4; ++j) {
          acc[2 * p + i][j] = __builtin_amdgcn_mfma_f32_16x16x32_bf16(af[i][0], bfr[j][0], acc[2 * p + i][j], 0, 0, 0);
          acc[2 * p + i][j] = __builtin_amdgcn_mfma_f32_16x16x32_bf16(af[i][1], bfr[j][1], acc[2 * p + i][j], 0, 0, 0);
        }
      __builtin_amdgcn_s_setprio(0);
      if (p == 3) {
        if (t < NT - 2)       { VMW(4); }   // tile t+1 fully landed
        else if (t == NT - 2) { VMW(0); }   // drain for final tile
      }
      BAR();
    }
  }
  #undef STG
}

// QKV projection: x[8192,1024] * W[1024,1024]^T + b, fused over Q/K/V.
// blockIdx.y = sel*4 + nb (nb = 256-wide col block). Q,K row-major bf16;
// V stored transposed per batch: Vt[b][d][m].
__global__ __launch_bounds__(512, 2) void gemm_qkv(
    const unsigned short* __restrict__ xh,
    const unsigned short* __restrict__ wh,
    const float* __restrict__ bq, const float* __restrict__ bk, const float* __restrict__ bv,
    unsigned short* __restrict__ Qh, unsigned short* __restrict__ Kh,
    unsigned short* __restrict__ Vth)
{
  __shared__ __align__(16) unsigned short lds[65536];   // 128 KiB
  const int Mblk = blockIdx.x * 256;
  const int sel  = blockIdx.y >> 2;   // 0=Q 1=K 2=V
  const int nb   = blockIdx.y & 3;    // 256-wide col block within 1024

  const unsigned short* A = xh + (long)Mblk * 1024;
  const unsigned short* B = wh + sel * 1048576 + (long)(nb * 256) * 1024;
  const float* bias = (sel == 0) ? bq : (sel == 1) ? bk : bv;

  f32x4 acc[8][4] = {};
  gemm_core(A, B, 1024, 1024, 16, lds, acc);

  const int lane = threadIdx.x & 63, w = threadIdx.x >> 6;
  const int wr = w >> 2, wc = w & 3;
  const int lrow = lane & 15, kq = lane >> 4;

#pragma unroll
  for (int i = 0; i < 8; ++i) {
#pragma unroll
    for (int j = 0; j < 4; ++j) {
      const int col = nb * 256 + wc * 64 + j * 16 + lrow;   // output feature d
      const float bsv = bias[col];
#pragma unroll
      for (int r = 0; r < 4; ++r) {
        const int tok = Mblk + wr * 128 + i * 16 + kq * 4 + r;  // token index
        const unsigned short h = f2bf(acc[i][j][r] + bsv);
        if (sel == 2) {
          Vth[(long)(tok >> 11) * 2097152 + (long)col * 2048 + (tok & 2047)] = h;
        } else if (sel == 0) {
          Qh[(long)tok * 1024 + col] = h;
        } else {
          Kh[(long)tok * 1024 + col] = h;
        }
      }
    }
  }
}

// Batched NT GEMM, fp32 out: C[z] = alpha * A[z] * B[z]^T  (tile 256x256)
__global__ __launch_bounds__(512, 2) void gemm_f32out(
    const unsigned short* __restrict__ A, const unsigned short* __restrict__ B,
    int lda, int ldb, int NT,
    long sA, long sB, float* __restrict__ C, int ldc, long sC, float alpha)
{
  __shared__ __align__(16) unsigned short lds[65536];   // 128 KiB
  const int Mblk = blockIdx.x * 256;
  const int Nblk = blockIdx.y * 256;
  const long z = blockIdx.z;
  const unsigned short* Ab = A + z * sA + (long)Mblk * lda;
  const unsigned short* Bb = B + z * sB + (long)Nblk * ldb;
  float* Cb = C + z * sC;

  f32x4 acc[8][4] = {};
  gemm_core(Ab, Bb, lda, ldb, NT, lds, acc);

  const int lane = threadIdx.x & 63, w = threadIdx.x >> 6;
  const int wr = w >> 2, wc = w & 3;
  const int lrow = lane & 15, kq = lane >> 4;
#pragma unroll
  for (int i = 0; i < 8; ++i)
#pragma unroll
    for (int j = 0; j < 4; ++j)
#pragma unroll
      for (int r = 0; r < 4; ++r) {
        const int row = Mblk + wr * 128 + i * 16 + kq * 4 + r;
        const int col = Nblk + wc * 64 + j * 16 + lrow;
        Cb[(long)row * ldc + col] = alpha * acc[i][j][r];
      }
}

// Row softmax over 2048 entries, in place (fp32) + bf16 copy for the PV GEMM.
__global__ __launch_bounds__(256) void softmax_rows(
    float* __restrict__ S, unsigned short* __restrict__ Ph)
{
  __shared__ float red[4];
  const long row = blockIdx.x;
  float* rp = S + row * 2048;
  const int t = threadIdx.x;

  float x[8];
  *(float4*)&x[0] = reinterpret_cast<const float4*>(rp)[t];
  *(float4*)&x[4] = reinterpret_cast<const float4*>(rp)[t + 256];

  float m = x[0];
#pragma unroll
  for (int i = 1; i < 8; ++i) m = fmaxf(m, x[i]);
  for (int o = 32; o; o >>= 1) m = fmaxf(m, __shfl_xor(m, o, 64));
  if ((t & 63) == 0) red[t >> 6] = m;
  __syncthreads();
  m = fmaxf(fmaxf(red[0], red[1]), fmaxf(red[2], red[3]));
  __syncthreads();

  float s = 0.f;
#pragma unroll
  for (int i = 0; i < 8; ++i) { x[i] = expf(x[i] - m); s += x[i]; }
  for (int o = 32; o; o >>= 1) s += __shfl_xor(s, o, 64);
  if ((t & 63) == 0) red[t >> 6] = s;
  __syncthreads();
  s = (red[0] + red[1]) + (red[2] + red[3]);
  const float inv = 1.0f / s;

#pragma unroll
  for (int i = 0; i < 8; ++i) x[i] *= inv;
  reinterpret_cast<float4*>(rp)[t]       = *(float4*)&x[0];
  reinterpret_cast<float4*>(rp)[t + 256] = *(float4*)&x[4];

  const long b0 = row * 2048 + t * 4;
#pragma unroll
  for (int k = 0; k < 4; ++k) Ph[b0 + k] = f2bf(x[k]);
  const long b1 = row * 2048 + 1024 + t * 4;
#pragma unroll
  for (int k = 0; k < 4; ++k) Ph[b1 + k] = f2bf(x[4 + k]);
}

__global__ __launch_bounds__(256) void to_bf16(
    const float* __restrict__ x, unsigned short* __restrict__ hi, int n4)
{
  int i = blockIdx.x * 256 + threadIdx.x;
  const int stride = gridDim.x * 256;
  for (; i < n4; i += stride) {
    const float4 v = reinterpret_cast<const float4*>(x)[i];
    ushort4 h;
    h.x = f2bf(v.x); h.y = f2bf(v.y); h.z = f2bf(v.z); h.w = f2bf(v.w);
    reinterpret_cast<ushort4*>(hi)[i] = h;
  }
}

extern "C" void kernel_launch(void* const* d_in, const int* in_sizes, int n_in,
                              void* d_out, int out_size, void* d_ws, size_t ws_size,
                              hipStream_t stream)
{
  const float* x  = (const float*)d_in[0];
  const float* Wq = (const float*)d_in[1];
  const float* bq = (const float*)d_in[2];
  const float* Wk = (const float*)d_in[3];
  const float* bk = (const float*)d_in[4];
  const float* Wv = (const float*)d_in[5];
  const float* bv = (const float*)d_in[6];

  float* out  = (float*)d_out;                 // [4,2048,1024]
  float* attn = (float*)d_out + 8388608;       // [4,2048,2048]

  unsigned short* ws  = (unsigned short*)d_ws;
  unsigned short* xh  = ws;                    //  8,388,608
  unsigned short* wh  = xh + 8388608;          //  3,145,728 (Wq|Wk|Wv)
  unsigned short* Qh  = wh + 3145728;          //  8,388,608
  unsigned short* Kh  = Qh + 8388608;          //  8,388,608
  unsigned short* Vth = Kh + 8388608;          //  8,388,608  Vt[b][d][m]
  unsigned short* Ph  = Vth + 8388608;         // 16,777,216  P bf16

  to_bf16<<<2048, 256, 0, stream>>>(x, xh, 2097152);
  to_bf16<<<512, 256, 0, stream>>>(Wq, wh, 262144);
  to_bf16<<<512, 256, 0, stream>>>(Wk, wh + 1048576, 262144);
  to_bf16<<<512, 256, 0, stream>>>(Wv, wh + 2097152, 262144);

  // Q,K,V projections (M=8192, N=3x1024, K=1024): 384 blocks (256-tiles)
  gemm_qkv<<<dim3(32, 12), 512, 0, stream>>>(xh, wh, bq, bk, bv, Qh, Kh, Vth);

  // scores = Q K^T / 32 -> fp32 into d_out's attention slot: 256 blocks = 1/CU
  gemm_f32out<<<dim3(8, 8, 4), 512, 0, stream>>>(Qh, Kh, 1024, 1024, 16,
      2097152L, 2097152L, attn, 2048, 4194304L, 0.03125f);

  // softmax rows in place + emit P bf16
  softmax_rows<<<8192, 256, 0, stream>>>(attn, Ph);

  // out = P * Vt^T (K=2048 -> NT=32): 128 blocks
  gemm_f32out<<<dim3(8, 4, 4), 512, 0, stream>>>(Ph, Vth, 2048, 2048, 32,
      4194304L, 2097152L, out, 1024, 2097152L, 1.0f);
}

// Round 4
// 346.600 us; speedup vs baseline: 1.0150x; 1.0150x over previous
//
#include <hip/hip_runtime.h>
#include <cstdint>

typedef __attribute__((ext_vector_type(8))) short bf16x8;
typedef __attribute__((ext_vector_type(4))) float f32x4;

__device__ __forceinline__ unsigned short f2bf(float v) {
  unsigned u = __builtin_bit_cast(unsigned, v);
  u += 0x7FFFu + ((u >> 16) & 1u);   // RNE
  return (unsigned short)(u >> 16);
}

// async global->LDS, 16B per lane; LDS dest = wave-uniform base + lane*16
__device__ __forceinline__ void gload16(const unsigned short* g, unsigned short* l) {
  __builtin_amdgcn_global_load_lds(
      (const __attribute__((address_space(1))) void*)(uintptr_t)g,
      (__attribute__((address_space(3))) void*)(uint32_t)(uintptr_t)l,
      16, 0, 0);
}

// Single-pass bf16 NT GEMM core: C[128x128] += A[128xK] * B[128xK]^T, BK=64.
// (r0-proven structure: 2x __syncthreads per K-tile, 256 thr / 4 waves,
//  32 KiB LDS -> ~5 blocks/CU of TLP hides the staging drain.)
// LDS tile 128 rows x 64 shorts; XOR swizzle: row r's logical 16B chunk c at
// physical c ^ (r&7) -> conflict-free ds_read_b128, lane-contiguous staging.
__device__ __forceinline__ void gemm_core(
    const unsigned short* __restrict__ A, const unsigned short* __restrict__ B,
    int lda, int ldb, int K,
    unsigned short* ldsA, unsigned short* ldsB, f32x4 acc[4][4])
{
  const int tid  = threadIdx.x;
  const int wave = tid >> 6;
  const int lane = tid & 63;
  const int wm = (wave >> 1) * 64;
  const int wn = (wave & 1) * 64;
  const int lrow = lane & 15;
  const int kq = lane >> 4;

  // staging: wave w fills rows [w*32, w*32+32); lane covers row w*32+i*8+(lane>>3),
  // swizzled chunk (lane&7)^((lane>>3)&7); 4 calls per operand per K-chunk.
  const int sr = lane >> 3;                       // 0..7
  const int sc = (lane & 7) ^ (sr & 7);           // swizzled source chunk
  const unsigned short* ga = A + (long)(wave * 32 + sr) * lda + sc * 8;
  const unsigned short* gb = B + (long)(wave * 32 + sr) * ldb + sc * 8;
  unsigned short* lA = ldsA + wave * 2048;        // 4 KB slice per wave
  unsigned short* lB = ldsB + wave * 2048;

  const int pc0 = ((0 * 4 + kq) ^ (lrow & 7)) * 8;   // k-step 0 read chunk
  const int pc1 = ((1 * 4 + kq) ^ (lrow & 7)) * 8;   // k-step 1 read chunk

#pragma unroll 1
  for (int kb = 0; kb < K; kb += 64) {
    __syncthreads();  // previous tile fully consumed
#pragma unroll
    for (int i = 0; i < 4; ++i) {
      gload16(ga + kb + (long)i * 8 * lda, lA + i * 512);
      gload16(gb + kb + (long)i * 8 * ldb, lB + i * 512);
    }
    __syncthreads();  // drains vmcnt -> LDS valid

    bf16x8 af[4], bfr[4];
    // k-step 0 (k = kb .. kb+31)
#pragma unroll
    for (int i = 0; i < 4; ++i)
      af[i] = *(const bf16x8*)(ldsA + (wm + i * 16 + lrow) * 64 + pc0);
#pragma unroll
    for (int j = 0; j < 4; ++j)
      bfr[j] = *(const bf16x8*)(ldsB + (wn + j * 16 + lrow) * 64 + pc0);
#pragma unroll
    for (int i = 0; i < 4; ++i)
#pragma unroll
      for (int j = 0; j < 4; ++j)
        acc[i][j] = __builtin_amdgcn_mfma_f32_16x16x32_bf16(af[i], bfr[j], acc[i][j], 0, 0, 0);

    // k-step 1 (k = kb+32 .. kb+63)
#pragma unroll
    for (int i = 0; i < 4; ++i)
      af[i] = *(const bf16x8*)(ldsA + (wm + i * 16 + lrow) * 64 + pc1);
#pragma unroll
    for (int j = 0; j < 4; ++j)
      bfr[j] = *(const bf16x8*)(ldsB + (wn + j * 16 + lrow) * 64 + pc1);
#pragma unroll
    for (int i = 0; i < 4; ++i)
#pragma unroll
      for (int j = 0; j < 4; ++j)
        acc[i][j] = __builtin_amdgcn_mfma_f32_16x16x32_bf16(af[i], bfr[j], acc[i][j], 0, 0, 0);
  }
}

// QKV projection: x[8192,1024] * W[1024,1024]^T + b, fused over Q/K/V.
// 1D grid of 1536 blocks, XCD-clustered: lin%8 -> XCD g owns N-tiles
// y in [3g, 3g+3) x all 64 M-tiles (B working set 768 KB -> L2-resident;
// within-XCD order marches M for fixed y -> temporal B reuse).
// Q,K stored row-major bf16; V stored transposed per batch: Vt[b][d][m].
__global__ __launch_bounds__(256, 4) void gemm_qkv(
    const unsigned short* __restrict__ xh,
    const unsigned short* __restrict__ wh,
    const float* __restrict__ bq, const float* __restrict__ bk, const float* __restrict__ bv,
    unsigned short* __restrict__ Qh, unsigned short* __restrict__ Kh,
    unsigned short* __restrict__ Vth)
{
  __shared__ __align__(16) unsigned short ldsA[8192];
  __shared__ __align__(16) unsigned short ldsB[8192];
  // bijective XCD-cluster remap: lin (0..1535) -> (x: M-tile 0..63, y: 0..23)
  const int lin = blockIdx.x;
  const int xcd = lin & 7;
  const int idx = lin >> 3;            // 0..191
  const int bx  = idx & 63;            // M-tile
  const int by  = xcd * 3 + (idx >> 6);// N/sel tile 0..23

  const int Mblk = bx * 128;
  const int sel  = by >> 3;   // 0=Q 1=K 2=V
  const int nb   = by & 7;    // 128-wide col block within 1024

  const unsigned short* A = xh + (long)Mblk * 1024;
  const unsigned short* B = wh + sel * 1048576 + (long)(nb * 128) * 1024;
  const float* bias = (sel == 0) ? bq : (sel == 1) ? bk : bv;

  f32x4 acc[4][4] = {};
  gemm_core(A, B, 1024, 1024, 1024, ldsA, ldsB, acc);

  const int lane = threadIdx.x & 63, wave = threadIdx.x >> 6;
  const int wm = (wave >> 1) * 64, wn = (wave & 1) * 64;
  const int lrow = lane & 15, kq = lane >> 4;

#pragma unroll
  for (int i = 0; i < 4; ++i) {
#pragma unroll
    for (int j = 0; j < 4; ++j) {
      const int col = nb * 128 + wn + j * 16 + lrow;   // output feature d
      const float bsv = bias[col];
#pragma unroll
      for (int r = 0; r < 4; ++r) {
        const int tok = Mblk + wm + i * 16 + kq * 4 + r;  // token index
        const unsigned short h = f2bf(acc[i][j][r] + bsv);
        if (sel == 2) {
          Vth[(long)(tok >> 11) * 2097152 + (long)col * 2048 + (tok & 2047)] = h;
        } else if (sel == 0) {
          Qh[(long)tok * 1024 + col] = h;
        } else {
          Kh[(long)tok * 1024 + col] = h;
        }
      }
    }
  }
}

// Batched NT GEMM with fp32 output: C[z] = alpha * A[z] * B[z]^T.
// XCD-cluster remap per z-slice: 8 XCDs arranged as (nx x 8/nx) clusters of
// (xpc x ypc) tiles -> per-XCD working set fits its private L2; LLC re-reads
// drop from (Mtiles + Ntiles) to (cluster counts). Bijective by construction
// (requires gridDim.x == nx*xpc, gridDim.y == (8/nx)*ypc).
__global__ __launch_bounds__(256, 4) void gemm_f32out(
    const unsigned short* __restrict__ A, const unsigned short* __restrict__ B,
    int lda, int ldb, int K,
    long sA, long sB, float* __restrict__ C, int ldc, long sC, float alpha,
    int nx, int xpc, int ypc)
{
  __shared__ __align__(16) unsigned short ldsA[8192];
  __shared__ __align__(16) unsigned short ldsB[8192];
  const int lin = blockIdx.x + gridDim.x * blockIdx.y;
  const int xcd = lin & 7;
  const int idx = lin >> 3;
  const int cx = xcd % nx, cy = xcd / nx;
  const int bx = cx * xpc + idx % xpc;
  const int by = cy * ypc + idx / xpc;

  const int Mblk = bx * 128;
  const int Nblk = by * 128;
  const long z = blockIdx.z;
  const unsigned short* Ab = A + z * sA + (long)Mblk * lda;
  const unsigned short* Bb = B + z * sB + (long)Nblk * ldb;
  float* Cb = C + z * sC;

  f32x4 acc[4][4] = {};
  gemm_core(Ab, Bb, lda, ldb, K, ldsA, ldsB, acc);

  const int lane = threadIdx.x & 63, wave = threadIdx.x >> 6;
  const int wm = (wave >> 1) * 64, wn = (wave & 1) * 64;
  const int lrow = lane & 15, kq = lane >> 4;
#pragma unroll
  for (int i = 0; i < 4; ++i)
#pragma unroll
    for (int j = 0; j < 4; ++j)
#pragma unroll
      for (int r = 0; r < 4; ++r) {
        const int row = Mblk + wm + i * 16 + kq * 4 + r;
        const int col = Nblk + wn + j * 16 + lrow;
        Cb[(long)row * ldc + col] = alpha * acc[i][j][r];
      }
}

// Row softmax over 2048 entries, in place (fp32) + bf16 copy for the PV GEMM.
__global__ __launch_bounds__(256) void softmax_rows(
    float* __restrict__ S, unsigned short* __restrict__ Ph)
{
  __shared__ float red[4];
  const long row = blockIdx.x;
  float* rp = S + row * 2048;
  const int t = threadIdx.x;

  float x[8];
  *(float4*)&x[0] = reinterpret_cast<const float4*>(rp)[t];
  *(float4*)&x[4] = reinterpret_cast<const float4*>(rp)[t + 256];

  float m = x[0];
#pragma unroll
  for (int i = 1; i < 8; ++i) m = fmaxf(m, x[i]);
  for (int o = 32; o; o >>= 1) m = fmaxf(m, __shfl_xor(m, o, 64));
  if ((t & 63) == 0) red[t >> 6] = m;
  __syncthreads();
  m = fmaxf(fmaxf(red[0], red[1]), fmaxf(red[2], red[3]));
  __syncthreads();

  float s = 0.f;
#pragma unroll
  for (int i = 0; i < 8; ++i) { x[i] = expf(x[i] - m); s += x[i]; }
  for (int o = 32; o; o >>= 1) s += __shfl_xor(s, o, 64);
  if ((t & 63) == 0) red[t >> 6] = s;
  __syncthreads();
  s = (red[0] + red[1]) + (red[2] + red[3]);
  const float inv = 1.0f / s;

#pragma unroll
  for (int i = 0; i < 8; ++i) x[i] *= inv;
  reinterpret_cast<float4*>(rp)[t]       = *(float4*)&x[0];
  reinterpret_cast<float4*>(rp)[t + 256] = *(float4*)&x[4];

  const long b0 = row * 2048 + t * 4;
#pragma unroll
  for (int k = 0; k < 4; ++k) Ph[b0 + k] = f2bf(x[k]);
  const long b1 = row * 2048 + 1024 + t * 4;
#pragma unroll
  for (int k = 0; k < 4; ++k) Ph[b1 + k] = f2bf(x[4 + k]);
}

// One fused cast pass: x (2,097,152 float4) then Wq|Wk|Wv (262,144 float4 each).
__global__ __launch_bounds__(256) void to_bf16_all(
    const float* __restrict__ x,
    const float* __restrict__ Wq, const float* __restrict__ Wk,
    const float* __restrict__ Wv,
    unsigned short* __restrict__ xh, unsigned short* __restrict__ wh)
{
  const int stride = gridDim.x * 256;
  for (int i = blockIdx.x * 256 + threadIdx.x; i < 2883584; i += stride) {
    const float* src; unsigned short* dst; int off;
    if (i < 2097152)      { src = x;  dst = xh; off = i; }
    else {
      const int j = i - 2097152;
      const int sel = j >> 18;          // 0..2 (262144 float4 per W)
      off = j & 262143;
      src = (sel == 0) ? Wq : (sel == 1) ? Wk : Wv;
      dst = wh + (long)sel * 1048576;
    }
    const float4 v = reinterpret_cast<const float4*>(src)[off];
    ushort4 h;
    h.x = f2bf(v.x); h.y = f2bf(v.y); h.z = f2bf(v.z); h.w = f2bf(v.w);
    reinterpret_cast<ushort4*>(dst)[off] = h;
  }
}

extern "C" void kernel_launch(void* const* d_in, const int* in_sizes, int n_in,
                              void* d_out, int out_size, void* d_ws, size_t ws_size,
                              hipStream_t stream)
{
  const float* x  = (const float*)d_in[0];
  const float* Wq = (const float*)d_in[1];
  const float* bq = (const float*)d_in[2];
  const float* Wk = (const float*)d_in[3];
  const float* bk = (const float*)d_in[4];
  const float* Wv = (const float*)d_in[5];
  const float* bv = (const float*)d_in[6];

  float* out  = (float*)d_out;                 // [4,2048,1024]
  float* attn = (float*)d_out + 8388608;       // [4,2048,2048]

  unsigned short* ws  = (unsigned short*)d_ws;
  unsigned short* xh  = ws;                    //  8,388,608
  unsigned short* wh  = xh + 8388608;          //  3,145,728 (Wq|Wk|Wv)
  unsigned short* Qh  = wh + 3145728;          //  8,388,608
  unsigned short* Kh  = Qh + 8388608;          //  8,388,608
  unsigned short* Vth = Kh + 8388608;          //  8,388,608  Vt[b][d][m]
  unsigned short* Ph  = Vth + 8388608;         // 16,777,216  P bf16

  to_bf16_all<<<2048, 256, 0, stream>>>(x, Wq, Wk, Wv, xh, wh);

  // Q,K,V projections (M=8192, N=3x1024, K=1024), XCD-clustered 1D grid
  gemm_qkv<<<1536, 256, 0, stream>>>(xh, wh, bq, bk, bv, Qh, Kh, Vth);

  // scores = Q K^T / 32 -> fp32 straight into d_out's attention slot
  // cluster: 4x2 XCD grid of 4x8-tile clusters per z
  gemm_f32out<<<dim3(16, 16, 4), 256, 0, stream>>>(Qh, Kh, 1024, 1024, 1024,
      2097152L, 2097152L, attn, 2048, 4194304L, 0.03125f, 4, 4, 8);

  // softmax rows in place + emit P bf16
  softmax_rows<<<8192, 256, 0, stream>>>(attn, Ph);

  // out = P * Vt^T; cluster: 4x2 XCD grid of 4x4-tile clusters per z
  gemm_f32out<<<dim3(16, 8, 4), 256, 0, stream>>>(Ph, Vth, 2048, 2048, 2048,
      4194304L, 2097152L, out, 1024, 2097152L, 1.0f, 4, 4, 4);
}